// Round 7
// baseline (676.866 us; speedup 1.0000x reference)
//
#include <hip/hip_runtime.h>
#include <cstddef>
#include <cstdint>

// DiffMLA attention, MI355X.
// R13: attn LDS-pipe cuts on the proven R7 structure. Model (validated R7-R12):
// attn is LDS-throughput-bound at ~410 LDS-pipe cyc/wave-step (23 ds_read_b128
// + 16 ds_write_b16 + 5 gl_lds writes). Cuts: (1) V read per-lane from global
// (L2-resident) instead of LDS-staged -- unified 2-variant block kept (R9's
// variant-split doubled K traffic; its V-after-stageK issue order forced a
// vmcnt(0) drain). V loads issued BEFORE stageK so in-order vmcnt waits
// vmcnt(3) and the K prefetch stays in flight; sched_barrier(0) pins the order.
// (2) ones B-fragment is a register constant (l16==0 ? 1 : 0) -- no LDS read.
// __launch_bounds__(256,2): grid 512 = 2 blocks/CU, VGPR cap 256 (no R10 spill).
// v_allT back to linear [d][l] (MODE 5), V-read path correctness proven in R9.
// GEMM T1 XCD swizzle kept from R12.

namespace {

constexpr int kDC = 1024, kDim = 2048;
constexpr float kScale = 0.07216878364870323f;  // 1/sqrt(192)
constexpr int kTA = 2128;  // tmpAll row stride (c_kv 1024 | c_q 1024 | k_r 64 | lam 16)

typedef __bf16 bf16x8 __attribute__((ext_vector_type(8)));
typedef float f32x4 __attribute__((ext_vector_type(4)));

__device__ __forceinline__ unsigned short f2bf(float f) {
  __bf16 h = (__bf16)f;  // native v_cvt_pk_bf16_f32 (RTNE)
  return __builtin_bit_cast(unsigned short, h);
}
__device__ __forceinline__ float bf2f(unsigned short h) {
  union { unsigned int u; float f; } v; v.u = ((unsigned int)h) << 16;
  return v.f;
}
__device__ __forceinline__ f32x4 mfma16(bf16x8 a, bf16x8 b, f32x4 c) {
  return __builtin_amdgcn_mfma_f32_16x16x32_bf16(a, b, c, 0, 0, 0);
}
__device__ __forceinline__ void gl_lds16(const void* g, void* l) {
  __builtin_amdgcn_global_load_lds(
      (const __attribute__((address_space(1))) unsigned int*)g,
      (__attribute__((address_space(3))) unsigned int*)l, 16, 0, 0);
}
__device__ __forceinline__ void wait_lgkm0() {
  asm volatile("s_waitcnt lgkmcnt(0)" ::: "memory");
}

// ---------------- convert f32 -> bf16 ----------------
__global__ __launch_bounds__(256) void conv_bf16_kernel(const float* __restrict__ in,
                                                        unsigned short* __restrict__ out, int n4) {
  int e = blockIdx.x * 256 + threadIdx.x;
  if (e >= n4) return;
  float4 v = reinterpret_cast<const float4*>(in)[e];
  uint2 pk;
  pk.x = (unsigned int)f2bf(v.x) | ((unsigned int)f2bf(v.y) << 16);
  pk.y = (unsigned int)f2bf(v.z) | ((unsigned int)f2bf(v.w) << 16);
  reinterpret_cast<uint2*>(out)[e] = pk;
}

// ---------------- zero-fill bf16 region ----------------
__global__ __launch_bounds__(256) void zero_bf16_kernel(unsigned short* __restrict__ out, int n8) {
  int e = blockIdx.x * 256 + threadIdx.x;
  if (e >= n8) return;
  reinterpret_cast<uint4*>(out)[e] = uint4{0, 0, 0, 0};
}

// ------------- transpose+convert: in (K x N) f32 -> out (N x K) bf16 -------------
__global__ __launch_bounds__(256) void transpose_conv_kernel(const float* __restrict__ in,
                                                             unsigned short* __restrict__ out,
                                                             int K, int N) {
  __shared__ float t[32][33];
  int n0 = blockIdx.x * 32, k0 = blockIdx.y * 32;
  int tx = threadIdx.x & 31, ty = threadIdx.x >> 5;
#pragma unroll
  for (int i = 0; i < 4; i++) t[ty + i * 8][tx] = in[(size_t)(k0 + ty + i * 8) * N + n0 + tx];
  __syncthreads();
#pragma unroll
  for (int i = 0; i < 4; i++)
    out[(size_t)(n0 + ty + i * 8) * K + k0 + tx] = f2bf(t[tx][ty + i * 8]);
}

// ---- W_lambda_w (2048x16) -> wd_cat rows [2112,2128) bf16 ----
__global__ __launch_bounds__(256) void lamw_transpose_kernel(const float* __restrict__ in,
                                                             unsigned short* __restrict__ out) {
  int e = blockIdx.x * 256 + threadIdx.x;  // 16*2048
  if (e >= 16 * 2048) return;
  int k = e & 2047, n = e >> 11;
  out[(size_t)(2112 + n) * 2048 + k] = f2bf(in[(size_t)k * 16 + n]);
}

// ---------------- epilogue ----------------
// MODE 0: fp32 row-major C (stride N)
// MODE 4: fused down-proj: fp32 stride kTA; cols 0..1023 c_kv | 1024..2047 c_q
//         | 2048..2111 k_r | 2112..2127 lam_raw | >=2128 dropped
// MODE 5: fused UK|UV: gc<2048 -> k_all pack (XOR-swizzled d); else v_allT pack (LINEAR [d][l])
// MODE 6: fused UQ|QR: gc<4096 -> q_all pack (x kScale); else tmpB bf16 (stride 2048)
template <int MODE>
__device__ __forceinline__ void epi_store(void* dst, void* dst2, int gr, int gc, int N, float v) {
  if (MODE == 0) {
    reinterpret_cast<float*>(dst)[(size_t)gr * N + gc] = v;
  } else if (MODE == 4) {
    if (gc < kTA) reinterpret_cast<float*>(dst)[(size_t)gr * kTA + gc] = v;
  } else if (MODE == 5) {
    int bb = gr >> 11, l = gr & 2047;
    unsigned short hv = f2bf(v);
    if (gc < 2048) {
      int h = gc >> 7, d2 = gc & 127;
      int d2s = d2 ^ ((l & 7) << 3);  // K swizzle: 16B group XOR by row&7
      reinterpret_cast<unsigned short*>(dst)[((size_t)((bb * 16 + h) * 2048 + l)) * 192 + d2s] = hv;
    } else {
      int g2 = gc - 2048, h = g2 >> 7, d2 = g2 & 127;
      // V read directly from global by attn (no LDS staging) -> linear [d][l]
      reinterpret_cast<unsigned short*>(dst2)[((size_t)((bb * 16 + h) * 128 + d2)) * 2048 + l] = hv;
    }
  } else if (MODE == 6) {
    int bb = gr >> 11, l = gr & 2047;
    if (gc < 4096) {
      int h2 = gc >> 7, d2 = gc & 127;
      reinterpret_cast<unsigned short*>(dst)[((size_t)((bb * 32 + h2) * 2048 + l)) * 192 + d2] =
          f2bf(v * kScale);
    } else {
      reinterpret_cast<unsigned short*>(dst2)[(size_t)gr * 2048 + (gc - 4096)] = f2bf(v);
    }
  }
}

// ---- m97-structure GEMM: C(MxN) = A(MxK) * Bt(NxK)^T, 128x128 tile, BK=32 ----
// T1 XCD-aware bijective block swizzle (grids all %8==0).
template <int MODE>
__global__ __launch_bounds__(256) void gemm128_kernel(const unsigned short* __restrict__ A,
                                                      const unsigned short* __restrict__ Bt,
                                                      void* __restrict__ dst, void* __restrict__ dst2,
                                                      int M, int N, int K) {
  __shared__ unsigned short lds_a[128 * 32];
  __shared__ unsigned short lds_b[128 * 32];
  int tid = threadIdx.x, lane = tid & 63, w = tid >> 6;
  int quad = lane >> 4, l16 = lane & 15;
  int wr = w >> 1, wc = w & 1;
  int nwg = gridDim.x * gridDim.y;
  int bid = blockIdx.y * gridDim.x + blockIdx.x;
  int cpx = nwg >> 3;  // nwg % 8 == 0 for all our grids
  int swz = (bid & 7) * cpx + (bid >> 3);
  int bx = swz % gridDim.x, by = swz / gridDim.x;
  int mbase = by * 128, nbase = bx * 128;
  f32x4 acc[4][4] = {};
  int srow0 = tid >> 2, skoff = (tid & 3) * 8;
  const size_t a_base = (size_t)(mbase + srow0) * K + skoff;
  const size_t b_base = (size_t)(nbase + srow0) * K + skoff;
  unsigned short* lba0 = &lds_a[(size_t)(w * 64) * 8];
  unsigned short* lba1 = &lds_a[(size_t)(256 + w * 64) * 8];
  unsigned short* lbb0 = &lds_b[(size_t)(w * 64) * 8];
  unsigned short* lbb1 = &lds_b[(size_t)(256 + w * 64) * 8];
  for (int k0 = 0; k0 < K; k0 += 32) {
    __syncthreads();
    gl_lds16(&A[a_base + k0], lba0);
    gl_lds16(&A[a_base + (size_t)64 * K + k0], lba1);
    gl_lds16(&Bt[b_base + k0], lbb0);
    gl_lds16(&Bt[b_base + (size_t)64 * K + k0], lbb1);
    __syncthreads();
    bf16x8 af[4], bfr[4];
#pragma unroll
    for (int i = 0; i < 4; i++) {
      af[i] = *reinterpret_cast<const bf16x8*>(&lds_a[(wr * 64 + i * 16 + l16) * 32 + quad * 8]);
      bfr[i] = *reinterpret_cast<const bf16x8*>(&lds_b[(wc * 64 + i * 16 + l16) * 32 + quad * 8]);
    }
#pragma unroll
    for (int i = 0; i < 4; i++)
#pragma unroll
      for (int j = 0; j < 4; j++) acc[i][j] = mfma16(af[i], bfr[j], acc[i][j]);
  }
#pragma unroll
  for (int i = 0; i < 4; i++)
#pragma unroll
    for (int j = 0; j < 4; j++)
#pragma unroll
      for (int r = 0; r < 4; r++) {
        int gr = mbase + wr * 64 + i * 16 + quad * 4 + r;
        int gc = nbase + wc * 64 + j * 16 + l16;
        epi_store<MODE>(dst, dst2, gr, gc, N, acc[i][j][r]);
      }
}

// ---------------- RMS norm: tmpAll fp32 (rows x kTA, col offset) -> out bf16 ----------------
__global__ __launch_bounds__(256) void rms_kernel(const float* __restrict__ in,
                                                  const float* __restrict__ w,
                                                  unsigned short* __restrict__ out, int colOff) {
  int row = blockIdx.x, tid = threadIdx.x;
  float4 v = reinterpret_cast<const float4*>(in + (size_t)row * kTA + colOff)[tid];
  float ss = v.x * v.x + v.y * v.y + v.z * v.z + v.w * v.w;
  ss += __shfl_xor(ss, 1); ss += __shfl_xor(ss, 2); ss += __shfl_xor(ss, 4);
  ss += __shfl_xor(ss, 8); ss += __shfl_xor(ss, 16); ss += __shfl_xor(ss, 32);
  __shared__ float red[4];
  if ((tid & 63) == 0) red[tid >> 6] = ss;
  __syncthreads();
  float tot = red[0] + red[1] + red[2] + red[3];
  float rs = rsqrtf(tot * (1.0f / kDC) + 1e-6f);
  float4 wv = reinterpret_cast<const float4*>(w)[tid];
  uint2 pk;
  pk.x = (unsigned int)f2bf(v.x * rs * wv.x) | ((unsigned int)f2bf(v.y * rs * wv.y) << 16);
  pk.y = (unsigned int)f2bf(v.z * rs * wv.z) | ((unsigned int)f2bf(v.w * rs * wv.w) << 16);
  reinterpret_cast<uint2*>(out)[(size_t)row * 256 + tid] = pk;
}

// ---------------- RoPE ----------------
__device__ __forceinline__ float rope_val(float x1, float x2, int j, int l) {
  int i = j & 31;
  float inv_freq = powf(10000.0f, -(float)i * (1.0f / 32.0f));
  float ang = (float)l * inv_freq;
  float cv = cosf(ang), sv = sinf(ang);
  float rot = (j < 32) ? -x2 : x2;
  return x1 * cv + rot * sv;
}

// q_r: tmpB bf16 (4096 x 2048, col = h2*64+j) -> q_all[..., 128+j], x kScale
__global__ __launch_bounds__(256) void rope_q_kernel(const unsigned short* __restrict__ qr_raw,
                                                     unsigned short* __restrict__ q_all) {
  size_t e = (size_t)blockIdx.x * 256 + threadIdx.x;  // 4096*32*64
  int j = (int)(e & 63);
  int h2 = (int)((e >> 6) & 31);
  int bl = (int)(e >> 11);
  int l = bl & 2047, b = bl >> 11;
  float x1 = bf2f(qr_raw[(size_t)bl * 2048 + h2 * 64 + j]);
  float x2 = bf2f(qr_raw[(size_t)bl * 2048 + h2 * 64 + (j ^ 32)]);
  float val = rope_val(x1, x2, j, l) * kScale;
  q_all[((size_t)((b * 32 + h2) * 2048 + l)) * 192 + 128 + j] = f2bf(val);
}

// k_r: tmpAll cols 2048..2111 -> k_all[..., 128 + (j^swz)] broadcast to 16 heads
__global__ __launch_bounds__(256) void rope_k_kernel(const float* __restrict__ tmpAll,
                                                     unsigned short* __restrict__ k_all) {
  size_t e = (size_t)blockIdx.x * 256 + threadIdx.x;  // 4096*64
  int j = (int)(e & 63);
  int bl = (int)(e >> 6);
  int l = bl & 2047, b = bl >> 11;
  float x1 = tmpAll[(size_t)bl * kTA + 2048 + j];
  float x2 = tmpAll[(size_t)bl * kTA + 2048 + (j ^ 32)];
  unsigned short hv = f2bf(rope_val(x1, x2, j, l));
  int js = j ^ ((l & 7) << 3);  // same 16B-group swizzle as MODE 5 K pack
#pragma unroll
  for (int h = 0; h < 16; h++)
    k_all[((size_t)((b * 16 + h) * 2048 + l)) * 192 + 128 + js] = hv;
}

// ---------------- lam = sigmoid(lam_raw + bias), from tmpAll cols 2112..2127 ----------------
__global__ __launch_bounds__(256) void lam_fin_kernel(const float* __restrict__ tmpAll,
                                                      const float* __restrict__ bl_,
                                                      float* __restrict__ lam) {
  int e = blockIdx.x * 256 + threadIdx.x;  // 4096*16
  if (e >= 4096 * 16) return;
  int n = e & 15, row = e >> 4;
  float z = tmpAll[(size_t)row * kTA + 2112 + n] + bl_[n];
  lam[e] = 1.f / (1.f + __expf(-z));
}

// ---------------- flash attention v7: R7 structure, V from global, ones in regs ----------------
// grid (16 heads, 16 qpairs, 2 batch). Each block: BOTH q-variants, qt = 31-qp
// then qt = qp (constant 66 tile-steps). K double-buffered in LDS (gl_lds, R7
// syncthreads discipline). V read per-lane from global (L2-resident, linear
// [head][d][l]) -- V loads issued BEFORE stageK so the in-order vmcnt lets the
// compiler wait vmcnt(3) for V while the 3 K-prefetch loads stay in flight.
__global__ __launch_bounds__(256, 2) void attn7_kernel(const unsigned short* __restrict__ q_all,
                                                       const unsigned short* __restrict__ k_all,
                                                       const unsigned short* __restrict__ v_allT,
                                                       unsigned short* __restrict__ attn_o) {
  __shared__ unsigned short lds_k[2][32 * 192];
  __shared__ unsigned short lds_p[8 * 640];
  int n = blockIdx.x, qp = blockIdx.y, b = blockIdx.z;
  int tid = threadIdx.x, lane = tid & 63, w = tid >> 6, quad = lane >> 4, l16 = lane & 15;
  const unsigned short* k_head = k_all + ((size_t)(b * 16 + n) * 2048) * 192;
  const unsigned short* v_head = v_allT + ((size_t)(b * 16 + n) * 128) * 2048;

  unsigned short* pw0 = &lds_p[(w * 2 + 0) * 640];
  unsigned short* pw1 = &lds_p[(w * 2 + 1) * 640];
  // Per-lane V base: B-fragment element [k=pos0+quad*8+j][n=l16] = v_allT[l16][pos].
  const unsigned short* v_lane = v_head + (size_t)l16 * 2048 + quad * 8;

  // Row-sum B-operand (ones in column n=0): register constant, no LDS.
  __bf16 onec = __builtin_bit_cast(__bf16, (unsigned short)(l16 == 0 ? 0x3F80 : 0));
  bf16x8 vone = {onec, onec, onec, onec, onec, onec, onec, onec};

  auto stageK = [&](int pos0, int buf) {
    const unsigned short* kg = k_head + (size_t)pos0 * 192 + w * 1536 + lane * 8;
    unsigned short* kl = &lds_k[buf][w * 1536];
    gl_lds16(kg, kl);
    gl_lds16(kg + 512, kl + 512);
    gl_lds16(kg + 1024, kl + 1024);
  };

#pragma unroll 1
  for (int phase = 0; phase < 2; ++phase) {
    // Long tile first (qt=31-qp), then short (qt=qp). nt is always even, so the
    // last compute of a phase reads K buffer 1; next phase's stageK(0,0) into
    // buffer 0 is race-free, and its first in-loop __syncthreads drains vmcnt
    // before buffer 0 is read (same discipline as R7).
    int qt = phase ? qp : (31 - qp);
    const unsigned short* q0_row =
        q_all + ((size_t)(b * 32 + 2 * n) * 2048 + qt * 64 + w * 16 + l16) * 192;
    const unsigned short* q1_row = q0_row + (size_t)2048 * 192;

    bf16x8 qf0[6], qf1[6];
#pragma unroll
    for (int ks = 0; ks < 6; ks++) {
      qf0[ks] = *reinterpret_cast<const bf16x8*>(&q0_row[ks * 32 + quad * 8]);
      qf1[ks] = *reinterpret_cast<const bf16x8*>(&q1_row[ks * 32 + quad * 8]);
    }

    f32x4 acc0[9] = {}, acc1[9] = {};
    int qlo = qt * 64 + w * 16;
    int nt = 2 * qt + 2;

    stageK(0, 0);
    for (int kt = 0; kt < nt; kt++) {
      int cur = kt & 1;
      int pos0 = kt * 32;
      __syncthreads();  // drains stageK(kt) (vmcnt) + protects K buffer reuse
      bool active = (pos0 <= qlo + 15);
      bf16x8 vf[8];
      if (active) {
        // Issue V loads FIRST (oldest in vmcnt order).
        const unsigned short* vg = v_lane + pos0;
#pragma unroll
        for (int dt = 0; dt < 8; dt++)
          vf[dt] = *reinterpret_cast<const bf16x8*>(&vg[(size_t)dt * 16 * 2048]);
      }
      __builtin_amdgcn_sched_barrier(0);  // keep V older than the K prefetch below
      if (kt + 1 < nt) stageK((kt + 1) * 32, cur ^ 1);
      if (active) {
        const unsigned short* kb = &lds_k[cur][0];
        bool needmask = (pos0 + 31 > qlo);
        int ksw = (l16 & 7) << 3;
#pragma unroll
        for (int j = 0; j < 2; j++) {
          f32x4 s0 = {}, s1 = {};
#pragma unroll
          for (int ks = 0; ks < 6; ks++) {
            bf16x8 bK = *reinterpret_cast<const bf16x8*>(
                &kb[(j * 16 + l16) * 192 + ((ks * 32 + quad * 8) ^ ksw)]);
            s0 = mfma16(qf0[ks], bK, s0);
            s1 = mfma16(qf1[ks], bK, s1);
          }
#pragma unroll
          for (int r = 0; r < 4; r++) {
            bool msk = needmask && (pos0 + j * 16 + l16 > qlo + quad * 4 + r);
            float p0 = msk ? 0.f : __expf(s0[r]);
            float p1 = msk ? 0.f : __expf(s1[r]);
            pw0[(quad * 4 + r) * 40 + j * 16 + l16] = f2bf(p0);
            pw1[(quad * 4 + r) * 40 + j * 16 + l16] = f2bf(p1);
          }
        }
        wait_lgkm0();  // wave-local: P ds_writes committed before P ds_reads
        bf16x8 pf0 = *reinterpret_cast<const bf16x8*>(&pw0[l16 * 40 + quad * 8]);
        bf16x8 pf1 = *reinterpret_cast<const bf16x8*>(&pw1[l16 * 40 + quad * 8]);
#pragma unroll
        for (int dt = 0; dt < 8; dt++) {
          acc0[dt] = mfma16(pf0, vf[dt], acc0[dt]);
          acc1[dt] = mfma16(pf1, vf[dt], acc1[dt]);
        }
        acc0[8] = mfma16(pf0, vone, acc0[8]);
        acc1[8] = mfma16(pf1, vone, acc1[8]);
      }
    }

    unsigned short* o0 = attn_o + ((size_t)(b * 32 + 2 * n) * 2048 + qt * 64 + w * 16) * 128;
    unsigned short* o1 = o0 + (size_t)2048 * 128;
#pragma unroll
    for (int r = 0; r < 4; r++) {
      float li0 = __shfl(acc0[8][r], lane & 48);
      float li1 = __shfl(acc1[8][r], lane & 48);
      float inv0 = 1.f / li0, inv1 = 1.f / li1;
      int row = quad * 4 + r;
#pragma unroll
      for (int dt = 0; dt < 8; dt++) {
        o0[(size_t)row * 128 + dt * 16 + l16] = f2bf(acc0[dt][r] * inv0);
        o1[(size_t)row * 128 + dt * 16 + l16] = f2bf(acc1[dt][r] * inv1);
      }
    }
  }
}

// ---------------- combine (x8 vectorized): attn1 - lam*attn2 -> bf16 [bl][n*128+d] ----------------
__global__ __launch_bounds__(256) void combine_kernel(const unsigned short* __restrict__ attn_o,
                                                      const float* __restrict__ lam,
                                                      unsigned short* __restrict__ out) {
  size_t e = (size_t)blockIdx.x * 256 + threadIdx.x;  // over 4096*2048/8
  int c8 = (int)(e & 255);
  int bl = (int)(e >> 8);
  int n = c8 >> 4, dd = (c8 & 15) * 8;
  int b = bl >> 11, l = bl & 2047;
  size_t base = ((size_t)((b * 32 + n * 2) * 2048 + l)) * 128 + dd;
  uint4 a1 = *reinterpret_cast<const uint4*>(attn_o + base);
  uint4 a2 = *reinterpret_cast<const uint4*>(attn_o + base + (size_t)2048 * 128);
  float lm = lam[(size_t)bl * 16 + n];
  unsigned int r[4];
  const unsigned int* p1 = &a1.x;
  const unsigned int* p2 = &a2.x;
#pragma unroll
  for (int i = 0; i < 4; i++) {
    float lo = bf2f((unsigned short)(p1[i] & 0xFFFF)) - lm * bf2f((unsigned short)(p2[i] & 0xFFFF));
    float hi = bf2f((unsigned short)(p1[i] >> 16)) - lm * bf2f((unsigned short)(p2[i] >> 16));
    r[i] = (unsigned int)f2bf(lo) | ((unsigned int)f2bf(hi) << 16);
  }
  *reinterpret_cast<uint4*>(out + e * 8) = uint4{r[0], r[1], r[2], r[3]};
}

}  // namespace

extern "C" void kernel_launch(void* const* d_in, const int* in_sizes, int n_in,
                              void* d_out, int out_size, void* d_ws, size_t ws_size,
                              hipStream_t stream) {
  const float* x      = (const float*)d_in[0];
  const float* W_DKV  = (const float*)d_in[1];
  const float* kvnw   = (const float*)d_in[2];
  const float* W_UK   = (const float*)d_in[3];
  const float* W_UV   = (const float*)d_in[4];
  const float* W_DQ   = (const float*)d_in[5];
  const float* qnw    = (const float*)d_in[6];
  const float* W_UQ   = (const float*)d_in[7];
  const float* W_QR   = (const float*)d_in[8];
  const float* W_KR   = (const float*)d_in[9];
  const float* W_lw   = (const float*)d_in[10];
  const float* W_lb   = (const float*)d_in[11];
  const float* W_out  = (const float*)d_in[12];
  float* out = (float*)d_out;

  // ---- workspace carve ----
  char* ws = (char*)d_ws;
  size_t off = 0;
  auto alloc = [&](size_t bytes) { char* p = ws + off; off += (bytes + 255) & ~(size_t)255; return p; };
  unsigned short* xb     = (unsigned short*)alloc((size_t)4096 * 2048 * 2);
  unsigned short* wd_cat = (unsigned short*)alloc((size_t)2176 * 2048 * 2);  // [DKV|DQ|KR|LAMW|pad] x K
  unsigned short* wu_cat = (unsigned short*)alloc((size_t)4096 * 1024 * 2);  // [UK|UV] x K
  unsigned short* wuqr   = (unsigned short*)alloc((size_t)6144 * 1024 * 2);  // [UQ|QR] x K
  unsigned short* wout   = (unsigned short*)alloc((size_t)2048 * 2048 * 2);
  unsigned short* ckv    = (unsigned short*)alloc((size_t)4096 * 1024 * 2);
  unsigned short* cq     = (unsigned short*)alloc((size_t)4096 * 1024 * 2);
  unsigned short* k_all  = (unsigned short*)alloc((size_t)2 * 16 * 2048 * 192 * 2);
  unsigned short* v_allT = (unsigned short*)alloc((size_t)2 * 16 * 128 * 2048 * 2);
  unsigned short* q_all  = (unsigned short*)alloc((size_t)2 * 32 * 2048 * 192 * 2);
  unsigned short* attn_o = (unsigned short*)alloc((size_t)2 * 32 * 2048 * 128 * 2);
  unsigned short* attn_b = (unsigned short*)alloc((size_t)4096 * 2048 * 2);
  float* lam             = (float*)alloc((size_t)4096 * 16 * 4);
  float* tmpAll          = (float*)alloc((size_t)4096 * kTA * 4);
  unsigned short* tmpB   = (unsigned short*)tmpAll;  // aliased: tmpAll consumed before GEMM<6>
  (void)ws_size; (void)in_sizes; (void)n_in; (void)out_size;

  // ---- convert x; weights transposed to NxK bf16, concatenated along N ----
  hipLaunchKernelGGL(conv_bf16_kernel, dim3(8192), dim3(256), 0, stream, x, xb, 2097152);
  hipLaunchKernelGGL(transpose_conv_kernel, dim3(32, 64), dim3(256), 0, stream, W_DKV, wd_cat, 2048, 1024);
  hipLaunchKernelGGL(transpose_conv_kernel, dim3(32, 64), dim3(256), 0, stream, W_DQ,
                     wd_cat + (size_t)1024 * 2048, 2048, 1024);
  hipLaunchKernelGGL(transpose_conv_kernel, dim3(2, 64), dim3(256), 0, stream, W_KR,
                     wd_cat + (size_t)2048 * 2048, 2048, 64);
  hipLaunchKernelGGL(lamw_transpose_kernel, dim3(128), dim3(256), 0, stream, W_lw, wd_cat);
  hipLaunchKernelGGL(zero_bf16_kernel, dim3(48), dim3(256), 0, stream,
                     wd_cat + (size_t)2128 * 2048, 12288);  // pad rows [2128,2176)
  hipLaunchKernelGGL(transpose_conv_kernel, dim3(64, 32), dim3(256), 0, stream, W_UK, wu_cat, 1024, 2048);
  hipLaunchKernelGGL(transpose_conv_kernel, dim3(64, 32), dim3(256), 0, stream, W_UV,
                     wu_cat + (size_t)2048 * 1024, 1024, 2048);
  hipLaunchKernelGGL(transpose_conv_kernel, dim3(128, 32), dim3(256), 0, stream, W_UQ, wuqr, 1024, 4096);
  hipLaunchKernelGGL(transpose_conv_kernel, dim3(64, 32), dim3(256), 0, stream, W_QR,
                     wuqr + (size_t)4096 * 1024, 1024, 2048);
  hipLaunchKernelGGL(transpose_conv_kernel, dim3(64, 64), dim3(256), 0, stream, W_out, wout, 2048, 2048);

  // ---- fused down-proj (DKV|DQ|KR|LAMW): 544 blocks ----
  hipLaunchKernelGGL(gemm128_kernel<4>, dim3(17, 32), dim3(256), 0, stream,
                     xb, wd_cat, tmpAll, (void*)nullptr, 4096, 2176, 2048);
  hipLaunchKernelGGL(rms_kernel, dim3(4096), dim3(256), 0, stream, tmpAll, kvnw, ckv, 0);
  hipLaunchKernelGGL(rms_kernel, dim3(4096), dim3(256), 0, stream, tmpAll, qnw, cq, 1024);
  hipLaunchKernelGGL(rope_k_kernel, dim3(1024), dim3(256), 0, stream, tmpAll, k_all);
  hipLaunchKernelGGL(lam_fin_kernel, dim3(256), dim3(256), 0, stream, tmpAll, W_lb, lam);

  // ---- fused up-projections: UK|UV (1024 blocks), UQ|QR (1536 blocks) ----
  hipLaunchKernelGGL(gemm128_kernel<5>, dim3(32, 32), dim3(256), 0, stream,
                     ckv, wu_cat, k_all, v_allT, 4096, 4096, 1024);
  hipLaunchKernelGGL(gemm128_kernel<6>, dim3(48, 32), dim3(256), 0, stream,
                     cq, wuqr, q_all, tmpB, 4096, 6144, 1024);  // tmpB clobbers tmpAll (consumed)
  hipLaunchKernelGGL(rope_q_kernel, dim3(32768), dim3(256), 0, stream, tmpB, q_all);

  // ---- attention v7: unified block, V from global ----
  hipLaunchKernelGGL(attn7_kernel, dim3(16, 16, 2), dim3(256), 0, stream,
                     q_all, k_all, v_allT, attn_o);

  // ---- combine (x8) + output projection (512 blocks) ----
  hipLaunchKernelGGL(combine_kernel, dim3(4096), dim3(256), 0, stream, attn_o, lam, attn_b);
  hipLaunchKernelGGL(gemm128_kernel<0>, dim3(16, 32), dim3(256), 0, stream,
                     attn_b, wout, out, (void*)nullptr, 4096, 2048, 2048);
}

// Round 9
// 610.741 us; speedup vs baseline: 1.1083x; 1.1083x over previous
//
#include <hip/hip_runtime.h>
#include <cstddef>
#include <cstdint>

// DiffMLA attention, MI355X.
// R15 = R14 with the __exp2f -> exp2f compile fix (HIP device code has exp2f;
// __exp2f was resolving to the host glibc symbol and failing to compile).
// R14: GEMM K-loop pipelining (T3 "minimum 2-phase" recipe). The old loop was
// {barrier; stage; barrier(+vmcnt(0)); compute} -- stage issued then immediately
// drained, exposing ~200-300cy L2 latency every K-step (GEMM aggregate ~430 TF,
// ~370us of the 677us wall). New loop: double-buffered LDS (2x16KB=32KB, still
// 5 blocks/CU by LDS... 4 by waves), stage(t+1)->buf^1 issued BEFORE compute(t),
// ONE __syncthreads per iter at the end (its implicit vmcnt(0)+lgkm(0) drain is
// the exact guarantee both buffers need). Race audit: buf^1's last readers
// retired before end-of-(t-1) barrier; stage(t+1) lands before t+1's reads via
// end-of-t barrier. Also: rope powf -> exp2f (same math, ~100cy -> ~8cy).
// attn7 unchanged from R13 (165us control; in-register-softmax port parked).

namespace {

constexpr int kDC = 1024, kDim = 2048;
constexpr float kScale = 0.07216878364870323f;  // 1/sqrt(192)
constexpr int kTA = 2128;  // tmpAll row stride (c_kv 1024 | c_q 1024 | k_r 64 | lam 16)

typedef __bf16 bf16x8 __attribute__((ext_vector_type(8)));
typedef float f32x4 __attribute__((ext_vector_type(4)));

__device__ __forceinline__ unsigned short f2bf(float f) {
  __bf16 h = (__bf16)f;  // native v_cvt_pk_bf16_f32 (RTNE)
  return __builtin_bit_cast(unsigned short, h);
}
__device__ __forceinline__ float bf2f(unsigned short h) {
  union { unsigned int u; float f; } v; v.u = ((unsigned int)h) << 16;
  return v.f;
}
__device__ __forceinline__ f32x4 mfma16(bf16x8 a, bf16x8 b, f32x4 c) {
  return __builtin_amdgcn_mfma_f32_16x16x32_bf16(a, b, c, 0, 0, 0);
}
__device__ __forceinline__ void gl_lds16(const void* g, void* l) {
  __builtin_amdgcn_global_load_lds(
      (const __attribute__((address_space(1))) unsigned int*)g,
      (__attribute__((address_space(3))) unsigned int*)l, 16, 0, 0);
}
__device__ __forceinline__ void wait_lgkm0() {
  asm volatile("s_waitcnt lgkmcnt(0)" ::: "memory");
}

// ---------------- convert f32 -> bf16 ----------------
__global__ __launch_bounds__(256) void conv_bf16_kernel(const float* __restrict__ in,
                                                        unsigned short* __restrict__ out, int n4) {
  int e = blockIdx.x * 256 + threadIdx.x;
  if (e >= n4) return;
  float4 v = reinterpret_cast<const float4*>(in)[e];
  uint2 pk;
  pk.x = (unsigned int)f2bf(v.x) | ((unsigned int)f2bf(v.y) << 16);
  pk.y = (unsigned int)f2bf(v.z) | ((unsigned int)f2bf(v.w) << 16);
  reinterpret_cast<uint2*>(out)[e] = pk;
}

// ---------------- zero-fill bf16 region ----------------
__global__ __launch_bounds__(256) void zero_bf16_kernel(unsigned short* __restrict__ out, int n8) {
  int e = blockIdx.x * 256 + threadIdx.x;
  if (e >= n8) return;
  reinterpret_cast<uint4*>(out)[e] = uint4{0, 0, 0, 0};
}

// ------------- transpose+convert: in (K x N) f32 -> out (N x K) bf16 -------------
__global__ __launch_bounds__(256) void transpose_conv_kernel(const float* __restrict__ in,
                                                             unsigned short* __restrict__ out,
                                                             int K, int N) {
  __shared__ float t[32][33];
  int n0 = blockIdx.x * 32, k0 = blockIdx.y * 32;
  int tx = threadIdx.x & 31, ty = threadIdx.x >> 5;
#pragma unroll
  for (int i = 0; i < 4; i++) t[ty + i * 8][tx] = in[(size_t)(k0 + ty + i * 8) * N + n0 + tx];
  __syncthreads();
#pragma unroll
  for (int i = 0; i < 4; i++)
    out[(size_t)(n0 + ty + i * 8) * K + k0 + tx] = f2bf(t[tx][ty + i * 8]);
}

// ---- W_lambda_w (2048x16) -> wd_cat rows [2112,2128) bf16 ----
__global__ __launch_bounds__(256) void lamw_transpose_kernel(const float* __restrict__ in,
                                                             unsigned short* __restrict__ out) {
  int e = blockIdx.x * 256 + threadIdx.x;  // 16*2048
  if (e >= 16 * 2048) return;
  int k = e & 2047, n = e >> 11;
  out[(size_t)(2112 + n) * 2048 + k] = f2bf(in[(size_t)k * 16 + n]);
}

// ---------------- epilogue ----------------
// MODE 0: fp32 row-major C (stride N)
// MODE 4: fused down-proj: fp32 stride kTA; cols 0..1023 c_kv | 1024..2047 c_q
//         | 2048..2111 k_r | 2112..2127 lam_raw | >=2128 dropped
// MODE 5: fused UK|UV: gc<2048 -> k_all pack (XOR-swizzled d); else v_allT pack (LINEAR [d][l])
// MODE 6: fused UQ|QR: gc<4096 -> q_all pack (x kScale); else tmpB bf16 (stride 2048)
template <int MODE>
__device__ __forceinline__ void epi_store(void* dst, void* dst2, int gr, int gc, int N, float v) {
  if (MODE == 0) {
    reinterpret_cast<float*>(dst)[(size_t)gr * N + gc] = v;
  } else if (MODE == 4) {
    if (gc < kTA) reinterpret_cast<float*>(dst)[(size_t)gr * kTA + gc] = v;
  } else if (MODE == 5) {
    int bb = gr >> 11, l = gr & 2047;
    unsigned short hv = f2bf(v);
    if (gc < 2048) {
      int h = gc >> 7, d2 = gc & 127;
      int d2s = d2 ^ ((l & 7) << 3);  // K swizzle: 16B group XOR by row&7
      reinterpret_cast<unsigned short*>(dst)[((size_t)((bb * 16 + h) * 2048 + l)) * 192 + d2s] = hv;
    } else {
      int g2 = gc - 2048, h = g2 >> 7, d2 = g2 & 127;
      // V read directly from global by attn (no LDS staging) -> linear [d][l]
      reinterpret_cast<unsigned short*>(dst2)[((size_t)((bb * 16 + h) * 128 + d2)) * 2048 + l] = hv;
    }
  } else if (MODE == 6) {
    int bb = gr >> 11, l = gr & 2047;
    if (gc < 4096) {
      int h2 = gc >> 7, d2 = gc & 127;
      reinterpret_cast<unsigned short*>(dst)[((size_t)((bb * 32 + h2) * 2048 + l)) * 192 + d2] =
          f2bf(v * kScale);
    } else {
      reinterpret_cast<unsigned short*>(dst2)[(size_t)gr * 2048 + (gc - 4096)] = f2bf(v);
    }
  }
}

// ---- GEMM: C(MxN) = A(MxK) * Bt(NxK)^T, 128x128 tile, BK=32 ----
// R14: pipelined double-buffered K-loop. stage(t+1)->buf^1 issued BEFORE
// compute(t); one __syncthreads per iter (implicit vmcnt(0)+lgkm(0) drain
// guarantees stage(t+1) landed and buf^1's readers retired).
// T1 XCD-aware bijective block swizzle (grids all %8==0).
template <int MODE>
__global__ __launch_bounds__(256) void gemm128_kernel(const unsigned short* __restrict__ A,
                                                      const unsigned short* __restrict__ Bt,
                                                      void* __restrict__ dst, void* __restrict__ dst2,
                                                      int M, int N, int K) {
  __shared__ unsigned short lds_a[2][128 * 32];
  __shared__ unsigned short lds_b[2][128 * 32];
  int tid = threadIdx.x, lane = tid & 63, w = tid >> 6;
  int quad = lane >> 4, l16 = lane & 15;
  int wr = w >> 1, wc = w & 1;
  int nwg = gridDim.x * gridDim.y;
  int bid = blockIdx.y * gridDim.x + blockIdx.x;
  int cpx = nwg >> 3;  // nwg % 8 == 0 for all our grids
  int swz = (bid & 7) * cpx + (bid >> 3);
  int bx = swz % gridDim.x, by = swz / gridDim.x;
  int mbase = by * 128, nbase = bx * 128;
  f32x4 acc[4][4] = {};
  int srow0 = tid >> 2, skoff = (tid & 3) * 8;
  const size_t a_base = (size_t)(mbase + srow0) * K + skoff;
  const size_t b_base = (size_t)(nbase + srow0) * K + skoff;
  const int lofs = w * 512;  // per-wave staging offset (elements)

  auto stageAB = [&](int k0, int buf) {
    unsigned short* la = &lds_a[buf][lofs];
    unsigned short* lb = &lds_b[buf][lofs];
    gl_lds16(&A[a_base + k0], la);
    gl_lds16(&A[a_base + (size_t)64 * K + k0], la + 2048);
    gl_lds16(&Bt[b_base + k0], lb);
    gl_lds16(&Bt[b_base + (size_t)64 * K + k0], lb + 2048);
  };

  stageAB(0, 0);
  __syncthreads();  // drain stage(0); all waves' portions landed
  int nk = K >> 5;
#pragma unroll 1
  for (int t = 0; t < nk; ++t) {
    int cur = t & 1;
    if (t + 1 < nk) stageAB((t + 1) << 5, cur ^ 1);  // issue early; latency hides under compute
    bf16x8 af[4], bfr[4];
#pragma unroll
    for (int i = 0; i < 4; i++) {
      af[i] = *reinterpret_cast<const bf16x8*>(&lds_a[cur][(wr * 64 + i * 16 + l16) * 32 + quad * 8]);
      bfr[i] = *reinterpret_cast<const bf16x8*>(&lds_b[cur][(wc * 64 + i * 16 + l16) * 32 + quad * 8]);
    }
#pragma unroll
    for (int i = 0; i < 4; i++)
#pragma unroll
      for (int j = 0; j < 4; j++) acc[i][j] = mfma16(af[i], bfr[j], acc[i][j]);
    __syncthreads();  // stage(t+1) landed + buf readers retired; one barrier/iter
  }
#pragma unroll
  for (int i = 0; i < 4; i++)
#pragma unroll
    for (int j = 0; j < 4; j++)
#pragma unroll
      for (int r = 0; r < 4; r++) {
        int gr = mbase + wr * 64 + i * 16 + quad * 4 + r;
        int gc = nbase + wc * 64 + j * 16 + l16;
        epi_store<MODE>(dst, dst2, gr, gc, N, acc[i][j][r]);
      }
}

// ---------------- RMS norm: tmpAll fp32 (rows x kTA, col offset) -> out bf16 ----------------
__global__ __launch_bounds__(256) void rms_kernel(const float* __restrict__ in,
                                                  const float* __restrict__ w,
                                                  unsigned short* __restrict__ out, int colOff) {
  int row = blockIdx.x, tid = threadIdx.x;
  float4 v = reinterpret_cast<const float4*>(in + (size_t)row * kTA + colOff)[tid];
  float ss = v.x * v.x + v.y * v.y + v.z * v.z + v.w * v.w;
  ss += __shfl_xor(ss, 1); ss += __shfl_xor(ss, 2); ss += __shfl_xor(ss, 4);
  ss += __shfl_xor(ss, 8); ss += __shfl_xor(ss, 16); ss += __shfl_xor(ss, 32);
  __shared__ float red[4];
  if ((tid & 63) == 0) red[tid >> 6] = ss;
  __syncthreads();
  float tot = red[0] + red[1] + red[2] + red[3];
  float rs = rsqrtf(tot * (1.0f / kDC) + 1e-6f);
  float4 wv = reinterpret_cast<const float4*>(w)[tid];
  uint2 pk;
  pk.x = (unsigned int)f2bf(v.x * rs * wv.x) | ((unsigned int)f2bf(v.y * rs * wv.y) << 16);
  pk.y = (unsigned int)f2bf(v.z * rs * wv.z) | ((unsigned int)f2bf(v.w * rs * wv.w) << 16);
  reinterpret_cast<uint2*>(out)[(size_t)row * 256 + tid] = pk;
}

// ---------------- RoPE ----------------
__device__ __forceinline__ float rope_val(float x1, float x2, int j, int l) {
  int i = j & 31;
  // 10000^(-i/32) == exp2(-i * log2(10000)/32); log2(10000)/32 = 0.41524101186...
  float inv_freq = exp2f((float)i * -0.4152410119f);
  float ang = (float)l * inv_freq;
  float cv = cosf(ang), sv = sinf(ang);
  float rot = (j < 32) ? -x2 : x2;
  return x1 * cv + rot * sv;
}

// q_r: tmpB bf16 (4096 x 2048, col = h2*64+j) -> q_all[..., 128+j], x kScale
__global__ __launch_bounds__(256) void rope_q_kernel(const unsigned short* __restrict__ qr_raw,
                                                     unsigned short* __restrict__ q_all) {
  size_t e = (size_t)blockIdx.x * 256 + threadIdx.x;  // 4096*32*64
  int j = (int)(e & 63);
  int h2 = (int)((e >> 6) & 31);
  int bl = (int)(e >> 11);
  int l = bl & 2047, b = bl >> 11;
  float x1 = bf2f(qr_raw[(size_t)bl * 2048 + h2 * 64 + j]);
  float x2 = bf2f(qr_raw[(size_t)bl * 2048 + h2 * 64 + (j ^ 32)]);
  float val = rope_val(x1, x2, j, l) * kScale;
  q_all[((size_t)((b * 32 + h2) * 2048 + l)) * 192 + 128 + j] = f2bf(val);
}

// k_r: tmpAll cols 2048..2111 -> k_all[..., 128 + (j^swz)] broadcast to 16 heads
__global__ __launch_bounds__(256) void rope_k_kernel(const float* __restrict__ tmpAll,
                                                     unsigned short* __restrict__ k_all) {
  size_t e = (size_t)blockIdx.x * 256 + threadIdx.x;  // 4096*64
  int j = (int)(e & 63);
  int bl = (int)(e >> 6);
  int l = bl & 2047, b = bl >> 11;
  float x1 = tmpAll[(size_t)bl * kTA + 2048 + j];
  float x2 = tmpAll[(size_t)bl * kTA + 2048 + (j ^ 32)];
  unsigned short hv = f2bf(rope_val(x1, x2, j, l));
  int js = j ^ ((l & 7) << 3);  // same 16B-group swizzle as MODE 5 K pack
#pragma unroll
  for (int h = 0; h < 16; h++)
    k_all[((size_t)((b * 16 + h) * 2048 + l)) * 192 + 128 + js] = hv;
}

// ---------------- lam = sigmoid(lam_raw + bias), from tmpAll cols 2112..2127 ----------------
__global__ __launch_bounds__(256) void lam_fin_kernel(const float* __restrict__ tmpAll,
                                                      const float* __restrict__ bl_,
                                                      float* __restrict__ lam) {
  int e = blockIdx.x * 256 + threadIdx.x;  // 4096*16
  if (e >= 4096 * 16) return;
  int n = e & 15, row = e >> 4;
  float z = tmpAll[(size_t)row * kTA + 2112 + n] + bl_[n];
  lam[e] = 1.f / (1.f + __expf(-z));
}

// ---------------- flash attention v7: R7 structure, V from global, ones in regs ----------------
// grid (16 heads, 16 qpairs, 2 batch). Each block: BOTH q-variants, qt = 31-qp
// then qt = qp (constant 66 tile-steps). K double-buffered in LDS (gl_lds, R7
// syncthreads discipline). V read per-lane from global (L2-resident, linear
// [head][d][l]) -- V loads issued BEFORE stageK so the in-order vmcnt lets the
// compiler wait vmcnt(3) for V while the 3 K-prefetch loads stay in flight.
__global__ __launch_bounds__(256, 2) void attn7_kernel(const unsigned short* __restrict__ q_all,
                                                       const unsigned short* __restrict__ k_all,
                                                       const unsigned short* __restrict__ v_allT,
                                                       unsigned short* __restrict__ attn_o) {
  __shared__ unsigned short lds_k[2][32 * 192];
  __shared__ unsigned short lds_p[8 * 640];
  int n = blockIdx.x, qp = blockIdx.y, b = blockIdx.z;
  int tid = threadIdx.x, lane = tid & 63, w = tid >> 6, quad = lane >> 4, l16 = lane & 15;
  const unsigned short* k_head = k_all + ((size_t)(b * 16 + n) * 2048) * 192;
  const unsigned short* v_head = v_allT + ((size_t)(b * 16 + n) * 128) * 2048;

  unsigned short* pw0 = &lds_p[(w * 2 + 0) * 640];
  unsigned short* pw1 = &lds_p[(w * 2 + 1) * 640];
  // Per-lane V base: B-fragment element [k=pos0+quad*8+j][n=l16] = v_allT[l16][pos].
  const unsigned short* v_lane = v_head + (size_t)l16 * 2048 + quad * 8;

  // Row-sum B-operand (ones in column n=0): register constant, no LDS.
  __bf16 onec = __builtin_bit_cast(__bf16, (unsigned short)(l16 == 0 ? 0x3F80 : 0));
  bf16x8 vone = {onec, onec, onec, onec, onec, onec, onec, onec};

  auto stageK = [&](int pos0, int buf) {
    const unsigned short* kg = k_head + (size_t)pos0 * 192 + w * 1536 + lane * 8;
    unsigned short* kl = &lds_k[buf][w * 1536];
    gl_lds16(kg, kl);
    gl_lds16(kg + 512, kl + 512);
    gl_lds16(kg + 1024, kl + 1024);
  };

#pragma unroll 1
  for (int phase = 0; phase < 2; ++phase) {
    // Long tile first (qt=31-qp), then short (qt=qp). nt is always even, so the
    // last compute of a phase reads K buffer 1; next phase's stageK(0,0) into
    // buffer 0 is race-free, and its first in-loop __syncthreads drains vmcnt
    // before buffer 0 is read (same discipline as R7).
    int qt = phase ? qp : (31 - qp);
    const unsigned short* q0_row =
        q_all + ((size_t)(b * 32 + 2 * n) * 2048 + qt * 64 + w * 16 + l16) * 192;
    const unsigned short* q1_row = q0_row + (size_t)2048 * 192;

    bf16x8 qf0[6], qf1[6];
#pragma unroll
    for (int ks = 0; ks < 6; ks++) {
      qf0[ks] = *reinterpret_cast<const bf16x8*>(&q0_row[ks * 32 + quad * 8]);
      qf1[ks] = *reinterpret_cast<const bf16x8*>(&q1_row[ks * 32 + quad * 8]);
    }

    f32x4 acc0[9] = {}, acc1[9] = {};
    int qlo = qt * 64 + w * 16;
    int nt = 2 * qt + 2;

    stageK(0, 0);
    for (int kt = 0; kt < nt; kt++) {
      int cur = kt & 1;
      int pos0 = kt * 32;
      __syncthreads();  // drains stageK(kt) (vmcnt) + protects K buffer reuse
      bool active = (pos0 <= qlo + 15);
      bf16x8 vf[8];
      if (active) {
        // Issue V loads FIRST (oldest in vmcnt order).
        const unsigned short* vg = v_lane + pos0;
#pragma unroll
        for (int dt = 0; dt < 8; dt++)
          vf[dt] = *reinterpret_cast<const bf16x8*>(&vg[(size_t)dt * 16 * 2048]);
      }
      __builtin_amdgcn_sched_barrier(0);  // keep V older than the K prefetch below
      if (kt + 1 < nt) stageK((kt + 1) * 32, cur ^ 1);
      if (active) {
        const unsigned short* kb = &lds_k[cur][0];
        bool needmask = (pos0 + 31 > qlo);
        int ksw = (l16 & 7) << 3;
#pragma unroll
        for (int j = 0; j < 2; j++) {
          f32x4 s0 = {}, s1 = {};
#pragma unroll
          for (int ks = 0; ks < 6; ks++) {
            bf16x8 bK = *reinterpret_cast<const bf16x8*>(
                &kb[(j * 16 + l16) * 192 + ((ks * 32 + quad * 8) ^ ksw)]);
            s0 = mfma16(qf0[ks], bK, s0);
            s1 = mfma16(qf1[ks], bK, s1);
          }
#pragma unroll
          for (int r = 0; r < 4; r++) {
            bool msk = needmask && (pos0 + j * 16 + l16 > qlo + quad * 4 + r);
            float p0 = msk ? 0.f : __expf(s0[r]);
            float p1 = msk ? 0.f : __expf(s1[r]);
            pw0[(quad * 4 + r) * 40 + j * 16 + l16] = f2bf(p0);
            pw1[(quad * 4 + r) * 40 + j * 16 + l16] = f2bf(p1);
          }
        }
        wait_lgkm0();  // wave-local: P ds_writes committed before P ds_reads
        bf16x8 pf0 = *reinterpret_cast<const bf16x8*>(&pw0[l16 * 40 + quad * 8]);
        bf16x8 pf1 = *reinterpret_cast<const bf16x8*>(&pw1[l16 * 40 + quad * 8]);
#pragma unroll
        for (int dt = 0; dt < 8; dt++) {
          acc0[dt] = mfma16(pf0, vf[dt], acc0[dt]);
          acc1[dt] = mfma16(pf1, vf[dt], acc1[dt]);
        }
        acc0[8] = mfma16(pf0, vone, acc0[8]);
        acc1[8] = mfma16(pf1, vone, acc1[8]);
      }
    }

    unsigned short* o0 = attn_o + ((size_t)(b * 32 + 2 * n) * 2048 + qt * 64 + w * 16) * 128;
    unsigned short* o1 = o0 + (size_t)2048 * 128;
#pragma unroll
    for (int r = 0; r < 4; r++) {
      float li0 = __shfl(acc0[8][r], lane & 48);
      float li1 = __shfl(acc1[8][r], lane & 48);
      float inv0 = 1.f / li0, inv1 = 1.f / li1;
      int row = quad * 4 + r;
#pragma unroll
      for (int dt = 0; dt < 8; dt++) {
        o0[(size_t)row * 128 + dt * 16 + l16] = f2bf(acc0[dt][r] * inv0);
        o1[(size_t)row * 128 + dt * 16 + l16] = f2bf(acc1[dt][r] * inv1);
      }
    }
  }
}

// ---------------- combine (x8 vectorized): attn1 - lam*attn2 -> bf16 [bl][n*128+d] ----------------
__global__ __launch_bounds__(256) void combine_kernel(const unsigned short* __restrict__ attn_o,
                                                      const float* __restrict__ lam,
                                                      unsigned short* __restrict__ out) {
  size_t e = (size_t)blockIdx.x * 256 + threadIdx.x;  // over 4096*2048/8
  int c8 = (int)(e & 255);
  int bl = (int)(e >> 8);
  int n = c8 >> 4, dd = (c8 & 15) * 8;
  int b = bl >> 11, l = bl & 2047;
  size_t base = ((size_t)((b * 32 + n * 2) * 2048 + l)) * 128 + dd;
  uint4 a1 = *reinterpret_cast<const uint4*>(attn_o + base);
  uint4 a2 = *reinterpret_cast<const uint4*>(attn_o + base + (size_t)2048 * 128);
  float lm = lam[(size_t)bl * 16 + n];
  unsigned int r[4];
  const unsigned int* p1 = &a1.x;
  const unsigned int* p2 = &a2.x;
#pragma unroll
  for (int i = 0; i < 4; i++) {
    float lo = bf2f((unsigned short)(p1[i] & 0xFFFF)) - lm * bf2f((unsigned short)(p2[i] & 0xFFFF));
    float hi = bf2f((unsigned short)(p1[i] >> 16)) - lm * bf2f((unsigned short)(p2[i] >> 16));
    r[i] = (unsigned int)f2bf(lo) | ((unsigned int)f2bf(hi) << 16);
  }
  *reinterpret_cast<uint4*>(out + e * 8) = uint4{r[0], r[1], r[2], r[3]};
}

}  // namespace

extern "C" void kernel_launch(void* const* d_in, const int* in_sizes, int n_in,
                              void* d_out, int out_size, void* d_ws, size_t ws_size,
                              hipStream_t stream) {
  const float* x      = (const float*)d_in[0];
  const float* W_DKV  = (const float*)d_in[1];
  const float* kvnw   = (const float*)d_in[2];
  const float* W_UK   = (const float*)d_in[3];
  const float* W_UV   = (const float*)d_in[4];
  const float* W_DQ   = (const float*)d_in[5];
  const float* qnw    = (const float*)d_in[6];
  const float* W_UQ   = (const float*)d_in[7];
  const float* W_QR   = (const float*)d_in[8];
  const float* W_KR   = (const float*)d_in[9];
  const float* W_lw   = (const float*)d_in[10];
  const float* W_lb   = (const float*)d_in[11];
  const float* W_out  = (const float*)d_in[12];
  float* out = (float*)d_out;

  // ---- workspace carve ----
  char* ws = (char*)d_ws;
  size_t off = 0;
  auto alloc = [&](size_t bytes) { char* p = ws + off; off += (bytes + 255) & ~(size_t)255; return p; };
  unsigned short* xb     = (unsigned short*)alloc((size_t)4096 * 2048 * 2);
  unsigned short* wd_cat = (unsigned short*)alloc((size_t)2176 * 2048 * 2);  // [DKV|DQ|KR|LAMW|pad] x K
  unsigned short* wu_cat = (unsigned short*)alloc((size_t)4096 * 1024 * 2);  // [UK|UV] x K
  unsigned short* wuqr   = (unsigned short*)alloc((size_t)6144 * 1024 * 2);  // [UQ|QR] x K
  unsigned short* wout   = (unsigned short*)alloc((size_t)2048 * 2048 * 2);
  unsigned short* ckv    = (unsigned short*)alloc((size_t)4096 * 1024 * 2);
  unsigned short* cq     = (unsigned short*)alloc((size_t)4096 * 1024 * 2);
  unsigned short* k_all  = (unsigned short*)alloc((size_t)2 * 16 * 2048 * 192 * 2);
  unsigned short* v_allT = (unsigned short*)alloc((size_t)2 * 16 * 128 * 2048 * 2);
  unsigned short* q_all  = (unsigned short*)alloc((size_t)2 * 32 * 2048 * 192 * 2);
  unsigned short* attn_o = (unsigned short*)alloc((size_t)2 * 32 * 2048 * 128 * 2);
  unsigned short* attn_b = (unsigned short*)alloc((size_t)4096 * 2048 * 2);
  float* lam             = (float*)alloc((size_t)4096 * 16 * 4);
  float* tmpAll          = (float*)alloc((size_t)4096 * kTA * 4);
  unsigned short* tmpB   = (unsigned short*)tmpAll;  // aliased: tmpAll consumed before GEMM<6>
  (void)ws_size; (void)in_sizes; (void)n_in; (void)out_size;

  // ---- convert x; weights transposed to NxK bf16, concatenated along N ----
  hipLaunchKernelGGL(conv_bf16_kernel, dim3(8192), dim3(256), 0, stream, x, xb, 2097152);
  hipLaunchKernelGGL(transpose_conv_kernel, dim3(32, 64), dim3(256), 0, stream, W_DKV, wd_cat, 2048, 1024);
  hipLaunchKernelGGL(transpose_conv_kernel, dim3(32, 64), dim3(256), 0, stream, W_DQ,
                     wd_cat + (size_t)1024 * 2048, 2048, 1024);
  hipLaunchKernelGGL(transpose_conv_kernel, dim3(2, 64), dim3(256), 0, stream, W_KR,
                     wd_cat + (size_t)2048 * 2048, 2048, 64);
  hipLaunchKernelGGL(lamw_transpose_kernel, dim3(128), dim3(256), 0, stream, W_lw, wd_cat);
  hipLaunchKernelGGL(zero_bf16_kernel, dim3(48), dim3(256), 0, stream,
                     wd_cat + (size_t)2128 * 2048, 12288);  // pad rows [2128,2176)
  hipLaunchKernelGGL(transpose_conv_kernel, dim3(64, 32), dim3(256), 0, stream, W_UK, wu_cat, 1024, 2048);
  hipLaunchKernelGGL(transpose_conv_kernel, dim3(64, 32), dim3(256), 0, stream, W_UV,
                     wu_cat + (size_t)2048 * 1024, 1024, 2048);
  hipLaunchKernelGGL(transpose_conv_kernel, dim3(128, 32), dim3(256), 0, stream, W_UQ, wuqr, 1024, 4096);
  hipLaunchKernelGGL(transpose_conv_kernel, dim3(64, 32), dim3(256), 0, stream, W_QR,
                     wuqr + (size_t)4096 * 1024, 1024, 2048);
  hipLaunchKernelGGL(transpose_conv_kernel, dim3(64, 64), dim3(256), 0, stream, W_out, wout, 2048, 2048);

  // ---- fused down-proj (DKV|DQ|KR|LAMW): 544 blocks ----
  hipLaunchKernelGGL(gemm128_kernel<4>, dim3(17, 32), dim3(256), 0, stream,
                     xb, wd_cat, tmpAll, (void*)nullptr, 4096, 2176, 2048);
  hipLaunchKernelGGL(rms_kernel, dim3(4096), dim3(256), 0, stream, tmpAll, kvnw, ckv, 0);
  hipLaunchKernelGGL(rms_kernel, dim3(4096), dim3(256), 0, stream, tmpAll, qnw, cq, 1024);
  hipLaunchKernelGGL(rope_k_kernel, dim3(1024), dim3(256), 0, stream, tmpAll, k_all);
  hipLaunchKernelGGL(lam_fin_kernel, dim3(256), dim3(256), 0, stream, tmpAll, W_lb, lam);

  // ---- fused up-projections: UK|UV (1024 blocks), UQ|QR (1536 blocks) ----
  hipLaunchKernelGGL(gemm128_kernel<5>, dim3(32, 32), dim3(256), 0, stream,
                     ckv, wu_cat, k_all, v_allT, 4096, 4096, 1024);
  hipLaunchKernelGGL(gemm128_kernel<6>, dim3(48, 32), dim3(256), 0, stream,
                     cq, wuqr, q_all, tmpB, 4096, 6144, 1024);  // tmpB clobbers tmpAll (consumed)
  hipLaunchKernelGGL(rope_q_kernel, dim3(32768), dim3(256), 0, stream, tmpB, q_all);

  // ---- attention v7: unified block, V from global ----
  hipLaunchKernelGGL(attn7_kernel, dim3(16, 16, 2), dim3(256), 0, stream,
                     q_all, k_all, v_allT, attn_o);

  // ---- combine (x8) + output projection (512 blocks) ----
  hipLaunchKernelGGL(combine_kernel, dim3(4096), dim3(256), 0, stream, attn_o, lam, attn_b);
  hipLaunchKernelGGL(gemm128_kernel<0>, dim3(16, 32), dim3(256), 0, stream,
                     attn_b, wout, out, (void*)nullptr, 4096, 2048, 2048);
}